// Round 4
// baseline (66.737 us; speedup 1.0000x reference)
//
#include <hip/hip_runtime.h>
#include <hip/hip_cooperative_groups.h>
#include <math.h>

namespace cg = cooperative_groups;

using short8 = __attribute__((ext_vector_type(8))) short;
using f32x4 = __attribute__((ext_vector_type(4))) float;

#define MFMA16(a, b, c) __builtin_amdgcn_mfma_f32_16x16x32_bf16((a), (b), (c), 0, 0, 0)

namespace {
constexpr int NG_ = 256;
constexpr int H_ = 128;
constexpr int NTOT_ = 2048;
constexpr float SCALE_E = 0.08838834764831845f / 256.0f;  // (1/sqrt(H))/Ng

// workspace offsets in BYTES
constexpr size_t OFF_QA = 0;               // bf16 [2048][128] = [aq|bq]
constexpr size_t OFF_KA = 524288;          // bf16 [2048][128] = [ak|bk]
constexpr size_t OFF_VT = 1048576;         // bf16 [8][128][256] (d-major)
constexpr size_t OFF_CT = 1572864;         // bf16 [2048][128] sqrt(w)*cos
constexpr size_t OFF_ST = 2097152;         // bf16 [2048][128] sqrt(w)*sin
constexpr size_t OFF_E  = 2621440;         // bf16 [8][256][256] (fallback only)
constexpr size_t OFF_GF = 3670016;         // f32 [2048]
}  // namespace

__device__ __forceinline__ short f2bf(float x) {
  unsigned u = __float_as_uint(x);
  unsigned r = (u + 0x7FFFu + ((u >> 16) & 1u)) >> 16;
  return (short)r;
}
__device__ __forceinline__ float bf2f(short x) {
  return __uint_as_float(((unsigned)(unsigned short)x) << 16);
}
__device__ __forceinline__ float sigmoidf_(float x) { return 1.0f / (1.0f + expf(-x)); }
__device__ __forceinline__ float siluf_(float x) { return x / (1.0f + expf(-x)); }

__device__ __forceinline__ short8 neg8(short8 x) {
  short8 r;
#pragma unroll
  for (int i = 0; i < 8; ++i) r[i] = (short)(x[i] ^ (short)0x8000);
  return r;
}
// fragment read from a [rows][128] bf16 LDS tile, XOR-swizzled
__device__ __forceinline__ short8 ldf(const short* buf, int row, int kk) {
  return *(const short8*)&buf[(row * 128 + kk) ^ ((row & 7) << 3)];
}
// fragment read from a [rows][64] bf16 LDS tile, XOR-swizzled
__device__ __forceinline__ short8 ldf64(const short* buf, int row, int kk) {
  return *(const short8*)&buf[(row * 64 + kk) ^ ((row & 7) << 3)];
}

// =====================================================================
// Shared phase-1 body: GEMM+activations (bid<32) or trig tables (32..95)
// =====================================================================
__device__ void prep_body(
    int bid, int tid, short* smem,
    const float* __restrict__ nf, const float* __restrict__ Wqkv,
    const float* __restrict__ Wvg, const float* __restrict__ bvg,
    const float* __restrict__ Whg, const float* __restrict__ bhg,
    const float* __restrict__ Wmg, const float* __restrict__ bmg,
    const float* __restrict__ cell, const float* __restrict__ pos,
    const int* __restrict__ nvec, const float* __restrict__ w,
    short* __restrict__ QA, short* __restrict__ KA, short* __restrict__ VT,
    short* __restrict__ CT, short* __restrict__ ST, float* __restrict__ GF,
    float* __restrict__ out_gate) {
  if (bid < 32) {
    short* lA = smem;          // 128x128
    short* lB = smem + 16384;  // 256x128
    const int r_tile = bid >> 1, h = bid & 1;
    const int n0 = r_tile * 128, c0 = h * 256;
#pragma unroll
    for (int it = 0; it < 4; ++it) {
      int e = tid + it * 512;
      int row = e >> 4, c8 = (e & 15) * 8;
      const float* src = nf + (size_t)(n0 + row) * H_ + c8;
      float4 lo = *(const float4*)src, hi = *(const float4*)(src + 4);
      short8 v;
      v[0] = f2bf(lo.x); v[1] = f2bf(lo.y); v[2] = f2bf(lo.z); v[3] = f2bf(lo.w);
      v[4] = f2bf(hi.x); v[5] = f2bf(hi.y); v[6] = f2bf(hi.z); v[7] = f2bf(hi.w);
      *(short8*)&lA[(row * 128 + c8) ^ ((row & 7) << 3)] = v;
    }
#pragma unroll
    for (int it = 0; it < 8; ++it) {
      int e = tid + it * 512;
      int row = e >> 4, c8 = (e & 15) * 8;
      int wr_g = c0 + row;
      const float* src =
          (wr_g < 384 ? Wqkv + (size_t)wr_g * H_ : Wvg + (size_t)(wr_g - 384) * H_) + c8;
      float4 lo = *(const float4*)src, hi = *(const float4*)(src + 4);
      short8 v;
      v[0] = f2bf(lo.x); v[1] = f2bf(lo.y); v[2] = f2bf(lo.z); v[3] = f2bf(lo.w);
      v[4] = f2bf(hi.x); v[5] = f2bf(hi.y); v[6] = f2bf(hi.z); v[7] = f2bf(hi.w);
      *(short8*)&lB[(row * 128 + c8) ^ ((row & 7) << 3)] = v;
    }
    __syncthreads();
    const int wid = tid >> 6, lane = tid & 63;
    const int wrow = (wid >> 2) * 64, wcol = (wid & 3) * 64;
    const int frow = lane & 15, kq = (lane >> 4) * 8;
    f32x4 acc[4][4] = {};
#pragma unroll
    for (int ks = 0; ks < 4; ++ks) {
      int kk = ks * 32 + kq;
      short8 a[4], b[4];
#pragma unroll
      for (int i = 0; i < 4; ++i) {
        a[i] = ldf(lA, wrow + i * 16 + frow, kk);
        b[i] = ldf(lB, wcol + i * 16 + frow, kk);
      }
#pragma unroll
      for (int i = 0; i < 4; ++i)
#pragma unroll
        for (int j = 0; j < 4; ++j) acc[i][j] = MFMA16(a[i], b[j], acc[i][j]);
    }
    const int orow = (lane >> 4) * 4, ocol = lane & 15;
    __syncthreads();
    if (h == 0) {
#pragma unroll
      for (int i = 0; i < 4; ++i)
#pragma unroll
        for (int j = 0; j < 4; ++j) {
          int c = wcol + j * 16 + ocol;
#pragma unroll
          for (int r = 0; r < 4; ++r) {
            int node = n0 + wrow + i * 16 + orow + r;
            float val = siluf_(acc[i][j][r]);
            if (c < 128)
              QA[(size_t)node * 128 + (c & 1) * 64 + (c >> 1)] = f2bf(val);
            else {
              int ck = c - 128;
              KA[(size_t)node * 128 + (ck & 1) * 64 + (ck >> 1)] = f2bf(val);
            }
          }
        }
    } else {
      short* gate_sh = lB;  // 128x128 bf16
      if (wcol >= 128) {
#pragma unroll
        for (int i = 0; i < 4; ++i)
#pragma unroll
          for (int j = 0; j < 4; ++j) {
            int d = wcol - 128 + j * 16 + ocol;
#pragma unroll
            for (int r = 0; r < 4; ++r) {
              int nl = wrow + i * 16 + orow + r;
              gate_sh[nl * 128 + d] = f2bf(sigmoidf_(acc[i][j][r] + bvg[d]));
            }
          }
      }
      __syncthreads();
      if (wcol < 128) {
        const int g_idx = n0 >> 8, half = (n0 >> 7) & 1;
#pragma unroll
        for (int i = 0; i < 4; ++i)
#pragma unroll
          for (int j = 0; j < 4; ++j) {
            int d = wcol + j * 16 + ocol;
#pragma unroll
            for (int r = 0; r < 4; ++r) {
              int nl = wrow + i * 16 + orow + r;
              float gate = bf2f(gate_sh[nl * 128 + d]);
              VT[((size_t)(g_idx * 128 + d)) * 256 + half * 128 + nl] =
                  f2bf(acc[i][j][r] * gate);
            }
          }
      }
      if (tid < 128) {
        int nl = tid;
        float hg = 0.f, mg = 0.f;
#pragma unroll 8
        for (int c = 0; c < 128; ++c) {
          float s = bf2f(lA[((nl * 128 + (c & ~7)) ^ ((nl & 7) << 3)) + (c & 7)]);
          hg += s * Whg[c];
          mg += s * Wmg[c];
        }
        int node = n0 + nl;
        GF[node] = 1.0f + 0.2f * tanhf(hg + bhg[0]);
        out_gate[node] = sigmoidf_(mg + bmg[0]);
      }
    }
  } else {
    const int b = bid - 32;
    const int g = b >> 3, n0 = (b & 7) * 32;
    float* f_sh = (float*)smem;
    int* nv_sh = (int*)((char*)smem + 512);
    float* w_sh = (float*)((char*)smem + 2048);
    if (tid < 32) {
      const float* cg = cell + (size_t)g * 9;
      float A00 = cg[0], A01 = cg[3], A02 = cg[6];
      float A10 = cg[1], A11 = cg[4], A12 = cg[7];
      float A20 = cg[2], A21 = cg[5], A22 = cg[8];
      float b00 = A11 * A22 - A12 * A21;
      float b01 = A02 * A21 - A01 * A22;
      float b02 = A01 * A12 - A02 * A11;
      float b10 = A12 * A20 - A10 * A22;
      float b11 = A00 * A22 - A02 * A20;
      float b12 = A02 * A10 - A00 * A12;
      float b20 = A10 * A21 - A11 * A20;
      float b21 = A01 * A20 - A00 * A21;
      float b22 = A00 * A11 - A01 * A10;
      float det = A00 * b00 + A01 * b10 + A02 * b20;
      float inv = 1.0f / det;
      const int node = g * NG_ + n0 + tid;
      float p0 = pos[(size_t)node * 3 + 0];
      float p1 = pos[(size_t)node * 3 + 1];
      float p2 = pos[(size_t)node * 3 + 2];
      float f0 = (b00 * p0 + b01 * p1 + b02 * p2) * inv;
      float f1 = (b10 * p0 + b11 * p1 + b12 * p2) * inv;
      float f2 = (b20 * p0 + b21 * p1 + b22 * p2) * inv;
      f_sh[tid * 4 + 0] = f0 - floorf(f0);
      f_sh[tid * 4 + 1] = f1 - floorf(f1);
      f_sh[tid * 4 + 2] = f2 - floorf(f2);
    }
    if (tid < 128) {
      nv_sh[tid * 3 + 0] = nvec[((size_t)g * 128 + tid) * 3 + 0];
      nv_sh[tid * 3 + 1] = nvec[((size_t)g * 128 + tid) * 3 + 1];
      nv_sh[tid * 3 + 2] = nvec[((size_t)g * 128 + tid) * 3 + 2];
      w_sh[tid] = sqrtf(w[(size_t)g * 128 + tid]);
    }
    __syncthreads();
    const int n_l = tid >> 4, m0 = (tid & 15) * 8;
    float f0 = f_sh[n_l * 4 + 0], f1 = f_sh[n_l * 4 + 1], f2 = f_sh[n_l * 4 + 2];
    short8 pc, ps;
#pragma unroll
    for (int i = 0; i < 8; ++i) {
      int m = m0 + i;
      float dot = f0 * (float)nv_sh[m * 3] + f1 * (float)nv_sh[m * 3 + 1] +
                  f2 * (float)nv_sh[m * 3 + 2];
      float tr = dot - floorf(dot);
      float sn = __builtin_amdgcn_sinf(tr);
      float cs = __builtin_amdgcn_cosf(tr);
      float sq = w_sh[m];
      pc[i] = f2bf(sq * cs);
      ps[i] = f2bf(sq * sn);
    }
    const int node = g * NG_ + n0 + n_l;
    *(short8*)&CT[(size_t)node * 128 + m0] = pc;
    *(short8*)&ST[(size_t)node * 128 + m0] = ps;
  }
}

// =====================================================================
// Fused single-launch kernel (cooperative): prep -> grid.sync -> E*V
// =====================================================================
__global__ __launch_bounds__(512) void k_fused(
    const float* __restrict__ nf, const float* __restrict__ Wqkv,
    const float* __restrict__ Wvg, const float* __restrict__ bvg,
    const float* __restrict__ Whg, const float* __restrict__ bhg,
    const float* __restrict__ Wmg, const float* __restrict__ bmg,
    const float* __restrict__ cell, const float* __restrict__ pos,
    const int* __restrict__ nvec, const float* __restrict__ w,
    short* __restrict__ QA, short* __restrict__ KA, short* __restrict__ VT,
    short* __restrict__ CT, short* __restrict__ ST, float* __restrict__ GF,
    float* __restrict__ out_gate, float* __restrict__ out) {
  __shared__ short smem[61440];  // 120 KB
  const int tid = threadIdx.x;
  const int bid = blockIdx.x;

  prep_body(bid, tid, smem, nf, Wqkv, Wvg, bvg, Whg, bhg, Wmg, bmg, cell, pos,
            nvec, w, QA, KA, VT, CT, ST, GF, out_gate);

  cg::this_grid().sync();
  if (bid >= 32) return;

  // ---- phase 2: fused E*V. Block = group g, 64 output rows R0..R0+63.
  short* tQA = smem;           // 64x128
  short* tCr = smem + 8192;
  short* tSr = smem + 16384;
  short* tKA = smem + 24576;
  short* tCc = smem + 32768;
  short* tSc = smem + 40960;
  short* tV  = smem + 49152;   // 128(d) x 64(n')
  short* tE  = smem + 57344;   // 64x64
  const int g = bid >> 2;
  const int R0 = (bid & 3) * 64;
  const int gn = g * NG_;
  const int wid = tid >> 6, lane = tid & 63;
  const int frow = lane & 15, kq = (lane >> 4) * 8;
  const int orow = (lane >> 4) * 4, ocol = lane & 15;
  const int pr = (wid >> 2) * 32, pd = (wid & 3) * 32;   // PV wave tile
  const int wr2 = (wid >> 1) * 32, wc2 = (wid & 1) * 32; // E wave tile (wid<4)

  // stage row-side once
#pragma unroll
  for (int it = 0; it < 2; ++it) {
    int e = tid + it * 512;
    int row = e >> 4, c8 = (e & 15) * 8;
    int idx = (row * 128 + c8) ^ ((row & 7) << 3);
    size_t ga = (size_t)(gn + R0 + row) * 128 + c8;
    *(short8*)&tQA[idx] = *(const short8*)&QA[ga];
    *(short8*)&tCr[idx] = *(const short8*)&CT[ga];
    *(short8*)&tSr[idx] = *(const short8*)&ST[ga];
  }

  f32x4 oacc[2][2] = {};
  for (int c4 = 0; c4 < 4; ++c4) {
    const int C0 = c4 * 64;
    __syncthreads();  // prev-iter readers done (also orders row-side staging)
#pragma unroll
    for (int it = 0; it < 2; ++it) {
      int e = tid + it * 512;
      int row = e >> 4, c8 = (e & 15) * 8;
      int idx = (row * 128 + c8) ^ ((row & 7) << 3);
      size_t ga = (size_t)(gn + C0 + row) * 128 + c8;
      *(short8*)&tKA[idx] = *(const short8*)&KA[ga];
      *(short8*)&tCc[idx] = *(const short8*)&CT[ga];
      *(short8*)&tSc[idx] = *(const short8*)&ST[ga];
      int d = e >> 3, n8 = (e & 7) * 8;
      *(short8*)&tV[(d * 64 + n8) ^ ((d & 7) << 3)] =
          *(const short8*)&VT[((size_t)g * 128 + d) * 256 + C0 + n8];
    }
    __syncthreads();
    if (wid < 4) {
      f32x4 gc[2][2] = {}, gs[2][2] = {}, qc[2][2] = {}, qs[2][2] = {};
      // Gram over channels, K=128; KB derived from KA (half-swap + negate)
#pragma unroll
      for (int ks = 0; ks < 4; ++ks) {
        int kk = ks * 32 + kq, kk2 = (kk + 64) & 127;
        short8 aq[2], ka[2], kb[2];
#pragma unroll
        for (int i = 0; i < 2; ++i) {
          aq[i] = ldf(tQA, wr2 + i * 16 + frow, kk);
          ka[i] = ldf(tKA, wc2 + i * 16 + frow, kk);
          short8 t = ldf(tKA, wc2 + i * 16 + frow, kk2);
          kb[i] = (ks >= 2) ? neg8(t) : t;
        }
#pragma unroll
        for (int i = 0; i < 2; ++i)
#pragma unroll
          for (int j = 0; j < 2; ++j) {
            gc[i][j] = MFMA16(aq[i], ka[j], gc[i][j]);
            gs[i][j] = MFMA16(aq[i], kb[j], gs[i][j]);
          }
      }
      // trig Grams via X=[C|S], Y=[S|-C], K=256 packed
#pragma unroll
      for (int ks = 0; ks < 8; ++ks) {
        const bool lo = ks < 4;
        int kk = (ks & 3) * 32 + kq;
        short8 xr[2], yr[2], xc[2];
#pragma unroll
        for (int i = 0; i < 2; ++i) {
          short8 cr = ldf(tCr, wr2 + i * 16 + frow, kk);
          short8 sr = ldf(tSr, wr2 + i * 16 + frow, kk);
          xr[i] = lo ? cr : sr;
          yr[i] = lo ? sr : neg8(cr);
        }
#pragma unroll
        for (int j = 0; j < 2; ++j)
          xc[j] = ldf(lo ? tCc : tSc, wc2 + j * 16 + frow, kk);
#pragma unroll
        for (int i = 0; i < 2; ++i)
#pragma unroll
          for (int j = 0; j < 2; ++j) {
            qc[i][j] = MFMA16(xr[i], xc[j], qc[i][j]);
            qs[i][j] = MFMA16(yr[i], xc[j], qs[i][j]);
          }
      }
      // combine and bounce E tile to LDS (bf16)
#pragma unroll
      for (int i = 0; i < 2; ++i)
#pragma unroll
        for (int j = 0; j < 2; ++j) {
          int col = wc2 + j * 16 + ocol;
#pragma unroll
          for (int r = 0; r < 4; ++r) {
            int row = wr2 + i * 16 + orow + r;
            float ev = gc[i][j][r] * qc[i][j][r] + gs[i][j][r] * qs[i][j][r];
            tE[(row * 64 + col) ^ ((row & 7) << 3)] = f2bf(ev);
          }
        }
    }
    __syncthreads();
    // PV: all 8 waves, out tile 64(n) x 128(d), k = 64
#pragma unroll
    for (int ks = 0; ks < 2; ++ks) {
      int kk = ks * 32 + kq;
      short8 a[2], b[2];
#pragma unroll
      for (int i = 0; i < 2; ++i) a[i] = ldf64(tE, pr + i * 16 + frow, kk);
#pragma unroll
      for (int j = 0; j < 2; ++j) b[j] = ldf64(tV, pd + j * 16 + frow, kk);
#pragma unroll
      for (int i = 0; i < 2; ++i)
#pragma unroll
        for (int j = 0; j < 2; ++j) oacc[i][j] = MFMA16(a[i], b[j], oacc[i][j]);
    }
  }
  // epilogue
#pragma unroll
  for (int i = 0; i < 2; ++i)
#pragma unroll
    for (int r = 0; r < 4; ++r) {
      int node = gn + R0 + pr + i * 16 + orow + r;
      float fct = GF[node] * SCALE_E;
#pragma unroll
      for (int j = 0; j < 2; ++j)
        out[(size_t)node * H_ + pd + j * 16 + ocol] = oacc[i][j][r] * fct;
    }
}

// =====================================================================
// Fallback path (round-3 kernels), used only if cooperative launch fails
// =====================================================================
__global__ __launch_bounds__(512) void k_prep(
    const float* __restrict__ nf, const float* __restrict__ Wqkv,
    const float* __restrict__ Wvg, const float* __restrict__ bvg,
    const float* __restrict__ Whg, const float* __restrict__ bhg,
    const float* __restrict__ Wmg, const float* __restrict__ bmg,
    const float* __restrict__ cell, const float* __restrict__ pos,
    const int* __restrict__ nvec, const float* __restrict__ w,
    short* __restrict__ QA, short* __restrict__ KA, short* __restrict__ VT,
    short* __restrict__ CT, short* __restrict__ ST, float* __restrict__ GF,
    float* __restrict__ out_gate) {
  __shared__ short smem[49152];
  prep_body(blockIdx.x, threadIdx.x, smem, nf, Wqkv, Wvg, bvg, Whg, bhg, Wmg,
            bmg, cell, pos, nvec, w, QA, KA, VT, CT, ST, GF, out_gate);
}

__global__ __launch_bounds__(256) void k_E(
    const short* __restrict__ QA, const short* __restrict__ KA,
    const short* __restrict__ Ct, const short* __restrict__ St,
    short* __restrict__ E) {
  __shared__ short sm[49152];
  short* tQA = sm;
  short* tKA = sm + 8192;
  short* tCr = sm + 16384;
  short* tSr = sm + 24576;
  short* tCc = sm + 32768;
  short* tSc = sm + 40960;
  const int tid = threadIdx.x;
  const int R0 = blockIdx.x * 64, C0 = blockIdx.y * 64;
  const int g = blockIdx.z, gn = g * NG_;
#pragma unroll
  for (int it = 0; it < 4; ++it) {
    int e = tid + it * 256;
    int row = e >> 4, c8 = (e & 15) * 8;
    int idx = (row * 128 + c8) ^ ((row & 7) << 3);
    *(short8*)&tQA[idx] = *(const short8*)&QA[(size_t)(gn + R0 + row) * 128 + c8];
    *(short8*)&tKA[idx] = *(const short8*)&KA[(size_t)(gn + C0 + row) * 128 + c8];
    *(short8*)&tCr[idx] = *(const short8*)&Ct[(size_t)(gn + R0 + row) * 128 + c8];
    *(short8*)&tSr[idx] = *(const short8*)&St[(size_t)(gn + R0 + row) * 128 + c8];
    *(short8*)&tCc[idx] = *(const short8*)&Ct[(size_t)(gn + C0 + row) * 128 + c8];
    *(short8*)&tSc[idx] = *(const short8*)&St[(size_t)(gn + C0 + row) * 128 + c8];
  }
  __syncthreads();
  const int wid = tid >> 6, lane = tid & 63;
  const int wr = (wid >> 1) * 32, wc = (wid & 1) * 32;
  const int frow = lane & 15, kq = (lane >> 4) * 8;
  f32x4 gc[2][2] = {}, gs[2][2] = {}, cc[2][2] = {}, cs[2][2] = {};
#pragma unroll
  for (int ks = 0; ks < 4; ++ks) {
    int kk = ks * 32 + kq, kk2 = (kk + 64) & 127;
    short8 aq[2], ka[2], kb[2];
#pragma unroll
    for (int i = 0; i < 2; ++i) {
      aq[i] = ldf(tQA, wr + i * 16 + frow, kk);
      ka[i] = ldf(tKA, wc + i * 16 + frow, kk);
      short8 t = ldf(tKA, wc + i * 16 + frow, kk2);
      kb[i] = (ks >= 2) ? neg8(t) : t;
    }
#pragma unroll
    for (int i = 0; i < 2; ++i)
#pragma unroll
      for (int j = 0; j < 2; ++j) {
        gc[i][j] = MFMA16(aq[i], ka[j], gc[i][j]);
        gs[i][j] = MFMA16(aq[i], kb[j], gs[i][j]);
      }
  }
#pragma unroll
  for (int ks = 0; ks < 8; ++ks) {
    const bool lo = ks < 4;
    int kk = (ks & 3) * 32 + kq;
    short8 xr[2], yr[2], xc[2];
#pragma unroll
    for (int i = 0; i < 2; ++i) {
      short8 cr = ldf(tCr, wr + i * 16 + frow, kk);
      short8 sr = ldf(tSr, wr + i * 16 + frow, kk);
      xr[i] = lo ? cr : sr;
      yr[i] = lo ? sr : neg8(cr);
    }
#pragma unroll
    for (int j = 0; j < 2; ++j) xc[j] = ldf(lo ? tCc : tSc, wc + j * 16 + frow, kk);
#pragma unroll
    for (int i = 0; i < 2; ++i)
#pragma unroll
      for (int j = 0; j < 2; ++j) {
        cc[i][j] = MFMA16(xr[i], xc[j], cc[i][j]);
        cs[i][j] = MFMA16(yr[i], xc[j], cs[i][j]);
      }
  }
  const int orow = (lane >> 4) * 4, ocol = lane & 15;
#pragma unroll
  for (int i = 0; i < 2; ++i)
#pragma unroll
    for (int j = 0; j < 2; ++j) {
      int col = C0 + wc + j * 16 + ocol;
#pragma unroll
      for (int r = 0; r < 4; ++r) {
        int row = R0 + wr + i * 16 + orow + r;
        float e = gc[i][j][r] * cc[i][j][r] + gs[i][j][r] * cs[i][j][r];
        E[(size_t)(gn + row) * NG_ + col] = f2bf(e);
      }
    }
}

__global__ __launch_bounds__(128) void k_out(
    const short* __restrict__ E, const short* __restrict__ Vt,
    const float* __restrict__ GF, float* __restrict__ out) {
  __shared__ short lE[64 * 256];
  __shared__ short lV[64 * 256];
  const int tid = threadIdx.x;
  const int N0 = blockIdx.x * 64, D0 = blockIdx.y * 64;
  const int g = blockIdx.z;
  const int wid = tid >> 6, lane = tid & 63;
  const int wr = wid * 32;
  const int frow = lane & 15, kq = (lane >> 4) * 8;
#pragma unroll
  for (int it = 0; it < 16; ++it) {
    int e = tid + it * 128;
    int row = e >> 5, c8 = (e & 31) * 8;
    int idx = (row * 256 + c8) ^ ((row & 7) << 3);
    *(short8*)&lE[idx] = *(const short8*)&E[((size_t)g * NG_ + N0 + row) * 256 + c8];
    *(short8*)&lV[idx] = *(const short8*)&Vt[((size_t)g * 128 + D0 + row) * 256 + c8];
  }
  __syncthreads();
  f32x4 acc[2][4] = {};
#pragma unroll
  for (int ks = 0; ks < 8; ++ks) {
    int kk = ks * 32 + kq;
    short8 a[2], b[4];
#pragma unroll
    for (int i = 0; i < 2; ++i) {
      int ra = wr + i * 16 + frow;
      a[i] = *(short8*)&lE[(ra * 256 + kk) ^ ((ra & 7) << 3)];
    }
#pragma unroll
    for (int j = 0; j < 4; ++j) {
      int rb = j * 16 + frow;
      b[j] = *(short8*)&lV[(rb * 256 + kk) ^ ((rb & 7) << 3)];
    }
#pragma unroll
    for (int i = 0; i < 2; ++i)
#pragma unroll
      for (int j = 0; j < 4; ++j) acc[i][j] = MFMA16(a[i], b[j], acc[i][j]);
  }
  const int orow = (lane >> 4) * 4, ocol = lane & 15;
#pragma unroll
  for (int i = 0; i < 2; ++i)
#pragma unroll
    for (int r = 0; r < 4; ++r) {
      int gnode = g * NG_ + N0 + wr + i * 16 + orow + r;
      float fct = GF[gnode] * SCALE_E;
#pragma unroll
      for (int j = 0; j < 4; ++j) {
        out[(size_t)gnode * H_ + D0 + j * 16 + ocol] = acc[i][j][r] * fct;
      }
    }
}

extern "C" void kernel_launch(void* const* d_in, const int* in_sizes, int n_in,
                              void* d_out, int out_size, void* d_ws,
                              size_t ws_size, hipStream_t stream) {
  const float* node_feat = (const float*)d_in[0];
  const float* positions = (const float*)d_in[1];
  const float* cell = (const float*)d_in[2];
  const float* w = (const float*)d_in[3];
  const float* Wqkv = (const float*)d_in[4];
  const float* Wvg = (const float*)d_in[5];
  const float* bvg = (const float*)d_in[6];
  const float* Whg = (const float*)d_in[7];
  const float* bhg = (const float*)d_in[8];
  const float* Wmg = (const float*)d_in[9];
  const float* bmg = (const float*)d_in[10];
  const int* nvec = (const int*)d_in[11];
  float* out = (float*)d_out;
  char* ws = (char*)d_ws;

  short* QA = (short*)(ws + OFF_QA);
  short* KA = (short*)(ws + OFF_KA);
  short* VT = (short*)(ws + OFF_VT);
  short* CT = (short*)(ws + OFF_CT);
  short* ST = (short*)(ws + OFF_ST);
  short* E = (short*)(ws + OFF_E);
  float* GF = (float*)(ws + OFF_GF);
  float* out_gate = out + (size_t)NTOT_ * H_;

  void* kp[] = {(void*)&node_feat, (void*)&Wqkv, (void*)&Wvg, (void*)&bvg,
                (void*)&Whg,       (void*)&bhg,  (void*)&Wmg, (void*)&bmg,
                (void*)&cell,      (void*)&positions, (void*)&nvec, (void*)&w,
                (void*)&QA,        (void*)&KA,   (void*)&VT,  (void*)&CT,
                (void*)&ST,        (void*)&GF,   (void*)&out_gate, (void*)&out};
  hipError_t err = hipLaunchCooperativeKernel((const void*)k_fused, dim3(96),
                                              dim3(512), kp, 0, stream);
  if (err != hipSuccess) {
    // fallback: 3-kernel path (round-3 behavior)
    k_prep<<<96, 512, 0, stream>>>(node_feat, Wqkv, Wvg, bvg, Whg, bhg, Wmg,
                                   bmg, cell, positions, nvec, w, QA, KA, VT,
                                   CT, ST, GF, out_gate);
    k_E<<<dim3(4, 4, 8), 256, 0, stream>>>(QA, KA, CT, ST, E);
    k_out<<<dim3(4, 2, 8), 128, 0, stream>>>(E, VT, GF, out);
  }
}

// Round 5
// 31.232 us; speedup vs baseline: 2.1368x; 2.1368x over previous
//
#include <hip/hip_runtime.h>
#include <math.h>

using short8 = __attribute__((ext_vector_type(8))) short;
using f32x4 = __attribute__((ext_vector_type(4))) float;

#define MFMA16(a, b, c) __builtin_amdgcn_mfma_f32_16x16x32_bf16((a), (b), (c), 0, 0, 0)

namespace {
constexpr int NG_ = 256;
constexpr int H_ = 128;
constexpr int NTOT_ = 2048;
constexpr float SCALE_E = 0.08838834764831845f / 256.0f;  // (1/sqrt(H))/Ng

// workspace offsets in BYTES
constexpr size_t OFF_QA = 0;               // bf16 [2048][128] = [aq|bq]
constexpr size_t OFF_KA = 524288;          // bf16 [2048][128] = [ak|bk]
constexpr size_t OFF_VT = 1048576;         // bf16 [8][128][256] (d-major)
constexpr size_t OFF_CT = 1572864;         // bf16 [2048][128] sqrt(w)*cos
constexpr size_t OFF_ST = 2097152;         // bf16 [2048][128] sqrt(w)*sin
constexpr size_t OFF_GF = 2621440;         // f32 [2048]
}  // namespace

__device__ __forceinline__ short f2bf(float x) {
  unsigned u = __float_as_uint(x);
  unsigned r = (u + 0x7FFFu + ((u >> 16) & 1u)) >> 16;
  return (short)r;
}
__device__ __forceinline__ float bf2f(short x) {
  return __uint_as_float(((unsigned)(unsigned short)x) << 16);
}
__device__ __forceinline__ float sigmoidf_(float x) { return 1.0f / (1.0f + expf(-x)); }
__device__ __forceinline__ float siluf_(float x) { return x / (1.0f + expf(-x)); }

__device__ __forceinline__ short8 neg8(short8 x) {
  short8 r;
#pragma unroll
  for (int i = 0; i < 8; ++i) r[i] = (short)(x[i] ^ (short)0x8000);
  return r;
}
// fragment read from a [rows][128] bf16 LDS tile, XOR-swizzled
__device__ __forceinline__ short8 ldf(const short* buf, int row, int kk) {
  return *(const short8*)&buf[(row * 128 + kk) ^ ((row & 7) << 3)];
}
// fragment read from a [rows][64] bf16 LDS tile, XOR-swizzled
__device__ __forceinline__ short8 ldf64(const short* buf, int row, int kk) {
  return *(const short8*)&buf[(row * 64 + kk) ^ ((row & 7) << 3)];
}

// ================= K_prep: fused GEMM+activations (bid<32) + trig (32..95)
__global__ __launch_bounds__(512) void k_prep(
    const float* __restrict__ nf, const float* __restrict__ Wqkv,
    const float* __restrict__ Wvg, const float* __restrict__ bvg,
    const float* __restrict__ Whg, const float* __restrict__ bhg,
    const float* __restrict__ Wmg, const float* __restrict__ bmg,
    const float* __restrict__ cell, const float* __restrict__ pos,
    const int* __restrict__ nvec, const float* __restrict__ w,
    short* __restrict__ QA, short* __restrict__ KA, short* __restrict__ VT,
    short* __restrict__ CT, short* __restrict__ ST, float* __restrict__ GF,
    float* __restrict__ out_gate) {
  __shared__ short smem[49152];  // 96 KB
  const int tid = threadIdx.x;
  const int bid = blockIdx.x;
  if (bid < 32) {
    short* lA = smem;          // 128x128
    short* lB = smem + 16384;  // 256x128
    const int r_tile = bid >> 1, h = bid & 1;
    const int n0 = r_tile * 128, c0 = h * 256;
#pragma unroll
    for (int it = 0; it < 4; ++it) {
      int e = tid + it * 512;
      int row = e >> 4, c8 = (e & 15) * 8;
      const float* src = nf + (size_t)(n0 + row) * H_ + c8;
      float4 lo = *(const float4*)src, hi = *(const float4*)(src + 4);
      short8 v;
      v[0] = f2bf(lo.x); v[1] = f2bf(lo.y); v[2] = f2bf(lo.z); v[3] = f2bf(lo.w);
      v[4] = f2bf(hi.x); v[5] = f2bf(hi.y); v[6] = f2bf(hi.z); v[7] = f2bf(hi.w);
      *(short8*)&lA[(row * 128 + c8) ^ ((row & 7) << 3)] = v;
    }
#pragma unroll
    for (int it = 0; it < 8; ++it) {
      int e = tid + it * 512;
      int row = e >> 4, c8 = (e & 15) * 8;
      int wr_g = c0 + row;
      const float* src =
          (wr_g < 384 ? Wqkv + (size_t)wr_g * H_ : Wvg + (size_t)(wr_g - 384) * H_) + c8;
      float4 lo = *(const float4*)src, hi = *(const float4*)(src + 4);
      short8 v;
      v[0] = f2bf(lo.x); v[1] = f2bf(lo.y); v[2] = f2bf(lo.z); v[3] = f2bf(lo.w);
      v[4] = f2bf(hi.x); v[5] = f2bf(hi.y); v[6] = f2bf(hi.z); v[7] = f2bf(hi.w);
      *(short8*)&lB[(row * 128 + c8) ^ ((row & 7) << 3)] = v;
    }
    __syncthreads();
    const int wid = tid >> 6, lane = tid & 63;
    const int wrow = (wid >> 2) * 64, wcol = (wid & 3) * 64;
    const int frow = lane & 15, kq = (lane >> 4) * 8;
    f32x4 acc[4][4] = {};
#pragma unroll
    for (int ks = 0; ks < 4; ++ks) {
      int kk = ks * 32 + kq;
      short8 a[4], b[4];
#pragma unroll
      for (int i = 0; i < 4; ++i) {
        a[i] = ldf(lA, wrow + i * 16 + frow, kk);
        b[i] = ldf(lB, wcol + i * 16 + frow, kk);
      }
#pragma unroll
      for (int i = 0; i < 4; ++i)
#pragma unroll
        for (int j = 0; j < 4; ++j) acc[i][j] = MFMA16(a[i], b[j], acc[i][j]);
    }
    const int orow = (lane >> 4) * 4, ocol = lane & 15;
    __syncthreads();
    if (h == 0) {
#pragma unroll
      for (int i = 0; i < 4; ++i)
#pragma unroll
        for (int j = 0; j < 4; ++j) {
          int c = wcol + j * 16 + ocol;
#pragma unroll
          for (int r = 0; r < 4; ++r) {
            int node = n0 + wrow + i * 16 + orow + r;
            float val = siluf_(acc[i][j][r]);
            if (c < 128)
              QA[(size_t)node * 128 + (c & 1) * 64 + (c >> 1)] = f2bf(val);
            else {
              int ck = c - 128;
              KA[(size_t)node * 128 + (ck & 1) * 64 + (ck >> 1)] = f2bf(val);
            }
          }
        }
    } else {
      short* gate_sh = lB;  // 128x128 bf16
      if (wcol >= 128) {
#pragma unroll
        for (int i = 0; i < 4; ++i)
#pragma unroll
          for (int j = 0; j < 4; ++j) {
            int d = wcol - 128 + j * 16 + ocol;
#pragma unroll
            for (int r = 0; r < 4; ++r) {
              int nl = wrow + i * 16 + orow + r;
              gate_sh[nl * 128 + d] = f2bf(sigmoidf_(acc[i][j][r] + bvg[d]));
            }
          }
      }
      __syncthreads();
      if (wcol < 128) {
        const int g_idx = n0 >> 8, half = (n0 >> 7) & 1;
#pragma unroll
        for (int i = 0; i < 4; ++i)
#pragma unroll
          for (int j = 0; j < 4; ++j) {
            int d = wcol + j * 16 + ocol;
#pragma unroll
            for (int r = 0; r < 4; ++r) {
              int nl = wrow + i * 16 + orow + r;
              float gate = bf2f(gate_sh[nl * 128 + d]);
              VT[((size_t)(g_idx * 128 + d)) * 256 + half * 128 + nl] =
                  f2bf(acc[i][j][r] * gate);
            }
          }
      }
      if (tid < 128) {
        int nl = tid;
        float hg = 0.f, mg = 0.f;
#pragma unroll 8
        for (int c = 0; c < 128; ++c) {
          float s = bf2f(lA[((nl * 128 + (c & ~7)) ^ ((nl & 7) << 3)) + (c & 7)]);
          hg += s * Whg[c];
          mg += s * Wmg[c];
        }
        int node = n0 + nl;
        GF[node] = 1.0f + 0.2f * tanhf(hg + bhg[0]);
        out_gate[node] = sigmoidf_(mg + bmg[0]);
      }
    }
  } else {
    const int b = bid - 32;
    const int g = b >> 3, n0 = (b & 7) * 32;
    float* f_sh = (float*)smem;
    int* nv_sh = (int*)((char*)smem + 512);
    float* w_sh = (float*)((char*)smem + 2048);
    if (tid < 32) {
      const float* cg = cell + (size_t)g * 9;
      float A00 = cg[0], A01 = cg[3], A02 = cg[6];
      float A10 = cg[1], A11 = cg[4], A12 = cg[7];
      float A20 = cg[2], A21 = cg[5], A22 = cg[8];
      float b00 = A11 * A22 - A12 * A21;
      float b01 = A02 * A21 - A01 * A22;
      float b02 = A01 * A12 - A02 * A11;
      float b10 = A12 * A20 - A10 * A22;
      float b11 = A00 * A22 - A02 * A20;
      float b12 = A02 * A10 - A00 * A12;
      float b20 = A10 * A21 - A11 * A20;
      float b21 = A01 * A20 - A00 * A21;
      float b22 = A00 * A11 - A01 * A10;
      float det = A00 * b00 + A01 * b10 + A02 * b20;
      float inv = 1.0f / det;
      const int node = g * NG_ + n0 + tid;
      float p0 = pos[(size_t)node * 3 + 0];
      float p1 = pos[(size_t)node * 3 + 1];
      float p2 = pos[(size_t)node * 3 + 2];
      float f0 = (b00 * p0 + b01 * p1 + b02 * p2) * inv;
      float f1 = (b10 * p0 + b11 * p1 + b12 * p2) * inv;
      float f2 = (b20 * p0 + b21 * p1 + b22 * p2) * inv;
      f_sh[tid * 4 + 0] = f0 - floorf(f0);
      f_sh[tid * 4 + 1] = f1 - floorf(f1);
      f_sh[tid * 4 + 2] = f2 - floorf(f2);
    }
    if (tid < 128) {
      nv_sh[tid * 3 + 0] = nvec[((size_t)g * 128 + tid) * 3 + 0];
      nv_sh[tid * 3 + 1] = nvec[((size_t)g * 128 + tid) * 3 + 1];
      nv_sh[tid * 3 + 2] = nvec[((size_t)g * 128 + tid) * 3 + 2];
      w_sh[tid] = sqrtf(w[(size_t)g * 128 + tid]);
    }
    __syncthreads();
    const int n_l = tid >> 4, m0 = (tid & 15) * 8;
    float f0 = f_sh[n_l * 4 + 0], f1 = f_sh[n_l * 4 + 1], f2 = f_sh[n_l * 4 + 2];
    short8 pc, ps;
#pragma unroll
    for (int i = 0; i < 8; ++i) {
      int m = m0 + i;
      float dot = f0 * (float)nv_sh[m * 3] + f1 * (float)nv_sh[m * 3 + 1] +
                  f2 * (float)nv_sh[m * 3 + 2];
      float tr = dot - floorf(dot);
      float sn = __builtin_amdgcn_sinf(tr);
      float cs = __builtin_amdgcn_cosf(tr);
      float sq = w_sh[m];
      pc[i] = f2bf(sq * cs);
      ps[i] = f2bf(sq * sn);
    }
    const int node = g * NG_ + n0 + n_l;
    *(short8*)&CT[(size_t)node * 128 + m0] = pc;
    *(short8*)&ST[(size_t)node * 128 + m0] = ps;
  }
}

// ================= K_EV: fused E (never materialized) * V
// 64 blocks: g = bid>>3, 32 output rows R0 = (bid&7)*32. 512 threads, 8 waves.
// Each wave owns one 16x16 E fragment per column chunk; PV accumulates 32x128.
__global__ __launch_bounds__(512) void k_EV(
    const short* __restrict__ QA, const short* __restrict__ KA,
    const short* __restrict__ VT, const short* __restrict__ CT,
    const short* __restrict__ ST, const float* __restrict__ GF,
    float* __restrict__ out) {
  __shared__ short smem[47104];  // 92 KB
  short* tQ  = smem;             // 32x128
  short* tCr = smem + 4096;
  short* tSr = smem + 8192;
  short* tKA = smem + 12288;     // 64x128
  short* tCc = smem + 20480;
  short* tSc = smem + 28672;
  short* tV  = smem + 36864;     // 128(d) x 64(n')
  short* tE  = smem + 45056;     // 32x64
  const int tid = threadIdx.x;
  const int bid = blockIdx.x;
  const int g = bid >> 3;
  const int R0 = (bid & 7) * 32;
  const int gn = g * NG_;
  const int wid = tid >> 6, lane = tid & 63;
  const int frow = lane & 15, kq = (lane >> 4) * 8;
  const int orow = (lane >> 4) * 4, ocol = lane & 15;
  const int rfrag = wid >> 2;          // 0..1 : E row fragment
  const int cfrag = wid & 3;           // 0..3 : E col fragment / PV d-block

  // row-side staging (32 rows): one pass, 512 threads cover 32x16 short8
  {
    int row = tid >> 4, c8 = (tid & 15) * 8;
    int idx = (row * 128 + c8) ^ ((row & 7) << 3);
    size_t ga = (size_t)(gn + R0 + row) * 128 + c8;
    *(short8*)&tQ[idx] = *(const short8*)&QA[ga];
    *(short8*)&tCr[idx] = *(const short8*)&CT[ga];
    *(short8*)&tSr[idx] = *(const short8*)&ST[ga];
  }

  f32x4 oacc[2] = {};
  for (int c4 = 0; c4 < 4; ++c4) {
    const int C0 = c4 * 64;
    __syncthreads();  // prev-iter readers done; also orders row-side staging
    // stage column chunk: KA/Cc/Sc (64x128 each) + V (128x64)
#pragma unroll
    for (int it = 0; it < 2; ++it) {
      int e = tid + it * 512;
      int row = e >> 4, c8 = (e & 15) * 8;
      int idx = (row * 128 + c8) ^ ((row & 7) << 3);
      size_t ga = (size_t)(gn + C0 + row) * 128 + c8;
      *(short8*)&tKA[idx] = *(const short8*)&KA[ga];
      *(short8*)&tCc[idx] = *(const short8*)&CT[ga];
      *(short8*)&tSc[idx] = *(const short8*)&ST[ga];
      int d = e >> 3, n8 = (e & 7) * 8;
      *(short8*)&tV[(d * 64 + n8) ^ ((d & 7) << 3)] =
          *(const short8*)&VT[((size_t)g * 128 + d) * 256 + C0 + n8];
    }
    __syncthreads();
    // ---- E fragment: each wave computes one 16x16 frag at (rfrag, cfrag)
    f32x4 gc = {}, gs = {}, qc = {}, qs = {};
#pragma unroll
    for (int ks = 0; ks < 4; ++ks) {
      int kk = ks * 32 + kq, kk2 = (kk + 64) & 127;
      short8 aq = ldf(tQ, rfrag * 16 + frow, kk);
      short8 ka = ldf(tKA, cfrag * 16 + frow, kk);
      short8 t = ldf(tKA, cfrag * 16 + frow, kk2);
      short8 kb = (ks >= 2) ? neg8(t) : t;
      gc = MFMA16(aq, ka, gc);
      gs = MFMA16(aq, kb, gs);
    }
#pragma unroll
    for (int ks = 0; ks < 8; ++ks) {
      const bool lo = ks < 4;
      int kk = (ks & 3) * 32 + kq;
      short8 cr = ldf(tCr, rfrag * 16 + frow, kk);
      short8 sr = ldf(tSr, rfrag * 16 + frow, kk);
      short8 xr = lo ? cr : sr;
      short8 yr = lo ? sr : neg8(cr);
      short8 xc = ldf(lo ? tCc : tSc, cfrag * 16 + frow, kk);
      qc = MFMA16(xr, xc, qc);
      qs = MFMA16(yr, xc, qs);
    }
    // combine -> bounce E frag through LDS (bf16)
    {
      int col = cfrag * 16 + ocol;
#pragma unroll
      for (int r = 0; r < 4; ++r) {
        int row = rfrag * 16 + orow + r;
        float ev = gc[r] * qc[r] + gs[r] * qs[r];
        tE[(row * 64 + col) ^ ((row & 7) << 3)] = f2bf(ev);
      }
    }
    __syncthreads();
    // ---- PV: wave (rfrag, cfrag) -> out rows rfrag*16, d cols cfrag*32..+31
#pragma unroll
    for (int ks = 0; ks < 2; ++ks) {
      int kk = ks * 32 + kq;
      short8 a = ldf64(tE, rfrag * 16 + frow, kk);
#pragma unroll
      for (int j = 0; j < 2; ++j) {
        short8 b = ldf64(tV, cfrag * 32 + j * 16 + frow, kk);
        oacc[j] = MFMA16(a, b, oacc[j]);
      }
    }
  }
  // epilogue
#pragma unroll
  for (int r = 0; r < 4; ++r) {
    int node = gn + R0 + rfrag * 16 + orow + r;
    float fct = GF[node] * SCALE_E;
#pragma unroll
    for (int j = 0; j < 2; ++j)
      out[(size_t)node * H_ + cfrag * 32 + j * 16 + ocol] = oacc[j][r] * fct;
  }
}

extern "C" void kernel_launch(void* const* d_in, const int* in_sizes, int n_in,
                              void* d_out, int out_size, void* d_ws,
                              size_t ws_size, hipStream_t stream) {
  const float* node_feat = (const float*)d_in[0];
  const float* positions = (const float*)d_in[1];
  const float* cell = (const float*)d_in[2];
  const float* w = (const float*)d_in[3];
  const float* Wqkv = (const float*)d_in[4];
  const float* Wvg = (const float*)d_in[5];
  const float* bvg = (const float*)d_in[6];
  const float* Whg = (const float*)d_in[7];
  const float* bhg = (const float*)d_in[8];
  const float* Wmg = (const float*)d_in[9];
  const float* bmg = (const float*)d_in[10];
  const int* nvec = (const int*)d_in[11];
  float* out = (float*)d_out;
  char* ws = (char*)d_ws;

  short* QA = (short*)(ws + OFF_QA);
  short* KA = (short*)(ws + OFF_KA);
  short* VT = (short*)(ws + OFF_VT);
  short* CT = (short*)(ws + OFF_CT);
  short* ST = (short*)(ws + OFF_ST);
  float* GF = (float*)(ws + OFF_GF);
  float* out_gate = out + (size_t)NTOT_ * H_;

  k_prep<<<96, 512, 0, stream>>>(node_feat, Wqkv, Wvg, bvg, Whg, bhg, Wmg, bmg,
                                 cell, positions, nvec, w, QA, KA, VT, CT, ST,
                                 GF, out_gate);
  k_EV<<<64, 512, 0, stream>>>(QA, KA, VT, CT, ST, GF, out);
}

// Round 6
// 27.756 us; speedup vs baseline: 2.4044x; 1.1252x over previous
//
#include <hip/hip_runtime.h>
#include <math.h>

using short8 = __attribute__((ext_vector_type(8))) short;
using f32x4 = __attribute__((ext_vector_type(4))) float;

#define MFMA16(a, b, c) __builtin_amdgcn_mfma_f32_16x16x32_bf16((a), (b), (c), 0, 0, 0)

namespace {
constexpr int NG_ = 256;
constexpr int H_ = 128;
constexpr int NTOT_ = 2048;
constexpr float SCALE_E = 0.08838834764831845f / 256.0f;  // (1/sqrt(H))/Ng

// workspace offsets in BYTES
constexpr size_t OFF_QA = 0;               // bf16 [2048][128] = [aq|bq]
constexpr size_t OFF_KA = 524288;          // bf16 [2048][128] = [ak|bk]
constexpr size_t OFF_VT = 1048576;         // bf16 [8][128][256] (d-major)
constexpr size_t OFF_CT = 1572864;         // bf16 [2048][128] sqrt(w)*cos
constexpr size_t OFF_ST = 2097152;         // bf16 [2048][128] sqrt(w)*sin
constexpr size_t OFF_GF = 2621440;         // f32 [2048]
constexpr size_t OFF_PART = 2631680;       // f32 [8][8][4][32][128] = 4 MB
}  // namespace

__device__ __forceinline__ short f2bf(float x) {
  unsigned u = __float_as_uint(x);
  unsigned r = (u + 0x7FFFu + ((u >> 16) & 1u)) >> 16;
  return (short)r;
}
__device__ __forceinline__ float bf2f(short x) {
  return __uint_as_float(((unsigned)(unsigned short)x) << 16);
}
__device__ __forceinline__ float sigmoidf_(float x) { return 1.0f / (1.0f + expf(-x)); }
__device__ __forceinline__ float siluf_(float x) { return x / (1.0f + expf(-x)); }

__device__ __forceinline__ short8 neg8(short8 x) {
  short8 r;
#pragma unroll
  for (int i = 0; i < 8; ++i) r[i] = (short)(x[i] ^ (short)0x8000);
  return r;
}
// fragment read from a [rows][128] bf16 LDS tile, XOR-swizzled
__device__ __forceinline__ short8 ldf(const short* buf, int row, int kk) {
  return *(const short8*)&buf[(row * 128 + kk) ^ ((row & 7) << 3)];
}
// fragment read from a [rows][64] bf16 LDS tile, XOR-swizzled
__device__ __forceinline__ short8 ldf64(const short* buf, int row, int kk) {
  return *(const short8*)&buf[(row * 64 + kk) ^ ((row & 7) << 3)];
}

// ================= K_prep: fused GEMM+activations (bid<32) + trig (32..95)
__global__ __launch_bounds__(512) void k_prep(
    const float* __restrict__ nf, const float* __restrict__ Wqkv,
    const float* __restrict__ Wvg, const float* __restrict__ bvg,
    const float* __restrict__ Whg, const float* __restrict__ bhg,
    const float* __restrict__ Wmg, const float* __restrict__ bmg,
    const float* __restrict__ cell, const float* __restrict__ pos,
    const int* __restrict__ nvec, const float* __restrict__ w,
    short* __restrict__ QA, short* __restrict__ KA, short* __restrict__ VT,
    short* __restrict__ CT, short* __restrict__ ST, float* __restrict__ GF,
    float* __restrict__ out_gate) {
  __shared__ short smem[49152];  // 96 KB
  const int tid = threadIdx.x;
  const int bid = blockIdx.x;
  if (bid < 32) {
    short* lA = smem;          // 128x128
    short* lB = smem + 16384;  // 256x128
    const int r_tile = bid >> 1, h = bid & 1;
    const int n0 = r_tile * 128, c0 = h * 256;
#pragma unroll
    for (int it = 0; it < 4; ++it) {
      int e = tid + it * 512;
      int row = e >> 4, c8 = (e & 15) * 8;
      const float* src = nf + (size_t)(n0 + row) * H_ + c8;
      float4 lo = *(const float4*)src, hi = *(const float4*)(src + 4);
      short8 v;
      v[0] = f2bf(lo.x); v[1] = f2bf(lo.y); v[2] = f2bf(lo.z); v[3] = f2bf(lo.w);
      v[4] = f2bf(hi.x); v[5] = f2bf(hi.y); v[6] = f2bf(hi.z); v[7] = f2bf(hi.w);
      *(short8*)&lA[(row * 128 + c8) ^ ((row & 7) << 3)] = v;
    }
#pragma unroll
    for (int it = 0; it < 8; ++it) {
      int e = tid + it * 512;
      int row = e >> 4, c8 = (e & 15) * 8;
      int wr_g = c0 + row;
      const float* src =
          (wr_g < 384 ? Wqkv + (size_t)wr_g * H_ : Wvg + (size_t)(wr_g - 384) * H_) + c8;
      float4 lo = *(const float4*)src, hi = *(const float4*)(src + 4);
      short8 v;
      v[0] = f2bf(lo.x); v[1] = f2bf(lo.y); v[2] = f2bf(lo.z); v[3] = f2bf(lo.w);
      v[4] = f2bf(hi.x); v[5] = f2bf(hi.y); v[6] = f2bf(hi.z); v[7] = f2bf(hi.w);
      *(short8*)&lB[(row * 128 + c8) ^ ((row & 7) << 3)] = v;
    }
    __syncthreads();
    const int wid = tid >> 6, lane = tid & 63;
    const int wrow = (wid >> 2) * 64, wcol = (wid & 3) * 64;
    const int frow = lane & 15, kq = (lane >> 4) * 8;
    f32x4 acc[4][4] = {};
#pragma unroll
    for (int ks = 0; ks < 4; ++ks) {
      int kk = ks * 32 + kq;
      short8 a[4], b[4];
#pragma unroll
      for (int i = 0; i < 4; ++i) {
        a[i] = ldf(lA, wrow + i * 16 + frow, kk);
        b[i] = ldf(lB, wcol + i * 16 + frow, kk);
      }
#pragma unroll
      for (int i = 0; i < 4; ++i)
#pragma unroll
        for (int j = 0; j < 4; ++j) acc[i][j] = MFMA16(a[i], b[j], acc[i][j]);
    }
    const int orow = (lane >> 4) * 4, ocol = lane & 15;
    __syncthreads();
    if (h == 0) {
#pragma unroll
      for (int i = 0; i < 4; ++i)
#pragma unroll
        for (int j = 0; j < 4; ++j) {
          int c = wcol + j * 16 + ocol;
#pragma unroll
          for (int r = 0; r < 4; ++r) {
            int node = n0 + wrow + i * 16 + orow + r;
            float val = siluf_(acc[i][j][r]);
            if (c < 128)
              QA[(size_t)node * 128 + (c & 1) * 64 + (c >> 1)] = f2bf(val);
            else {
              int ck = c - 128;
              KA[(size_t)node * 128 + (ck & 1) * 64 + (ck >> 1)] = f2bf(val);
            }
          }
        }
    } else {
      short* gate_sh = lB;  // 128x128 bf16
      if (wcol >= 128) {
#pragma unroll
        for (int i = 0; i < 4; ++i)
#pragma unroll
          for (int j = 0; j < 4; ++j) {
            int d = wcol - 128 + j * 16 + ocol;
#pragma unroll
            for (int r = 0; r < 4; ++r) {
              int nl = wrow + i * 16 + orow + r;
              gate_sh[nl * 128 + d] = f2bf(sigmoidf_(acc[i][j][r] + bvg[d]));
            }
          }
      }
      __syncthreads();
      if (wcol < 128) {
        const int g_idx = n0 >> 8, half = (n0 >> 7) & 1;
#pragma unroll
        for (int i = 0; i < 4; ++i)
#pragma unroll
          for (int j = 0; j < 4; ++j) {
            int d = wcol + j * 16 + ocol;
#pragma unroll
            for (int r = 0; r < 4; ++r) {
              int nl = wrow + i * 16 + orow + r;
              float gate = bf2f(gate_sh[nl * 128 + d]);
              VT[((size_t)(g_idx * 128 + d)) * 256 + half * 128 + nl] =
                  f2bf(acc[i][j][r] * gate);
            }
          }
      }
      if (tid < 128) {
        int nl = tid;
        float hg = 0.f, mg = 0.f;
#pragma unroll 8
        for (int c = 0; c < 128; ++c) {
          float s = bf2f(lA[((nl * 128 + (c & ~7)) ^ ((nl & 7) << 3)) + (c & 7)]);
          hg += s * Whg[c];
          mg += s * Wmg[c];
        }
        int node = n0 + nl;
        GF[node] = 1.0f + 0.2f * tanhf(hg + bhg[0]);
        out_gate[node] = sigmoidf_(mg + bmg[0]);
      }
    }
  } else {
    const int b = bid - 32;
    const int g = b >> 3, n0 = (b & 7) * 32;
    float* f_sh = (float*)smem;
    int* nv_sh = (int*)((char*)smem + 512);
    float* w_sh = (float*)((char*)smem + 2048);
    if (tid < 32) {
      const float* cg = cell + (size_t)g * 9;
      float A00 = cg[0], A01 = cg[3], A02 = cg[6];
      float A10 = cg[1], A11 = cg[4], A12 = cg[7];
      float A20 = cg[2], A21 = cg[5], A22 = cg[8];
      float b00 = A11 * A22 - A12 * A21;
      float b01 = A02 * A21 - A01 * A22;
      float b02 = A01 * A12 - A02 * A11;
      float b10 = A12 * A20 - A10 * A22;
      float b11 = A00 * A22 - A02 * A20;
      float b12 = A02 * A10 - A00 * A12;
      float b20 = A10 * A21 - A11 * A20;
      float b21 = A01 * A20 - A00 * A21;
      float b22 = A00 * A11 - A01 * A10;
      float det = A00 * b00 + A01 * b10 + A02 * b20;
      float inv = 1.0f / det;
      const int node = g * NG_ + n0 + tid;
      float p0 = pos[(size_t)node * 3 + 0];
      float p1 = pos[(size_t)node * 3 + 1];
      float p2 = pos[(size_t)node * 3 + 2];
      float f0 = (b00 * p0 + b01 * p1 + b02 * p2) * inv;
      float f1 = (b10 * p0 + b11 * p1 + b12 * p2) * inv;
      float f2 = (b20 * p0 + b21 * p1 + b22 * p2) * inv;
      f_sh[tid * 4 + 0] = f0 - floorf(f0);
      f_sh[tid * 4 + 1] = f1 - floorf(f1);
      f_sh[tid * 4 + 2] = f2 - floorf(f2);
    }
    if (tid < 128) {
      nv_sh[tid * 3 + 0] = nvec[((size_t)g * 128 + tid) * 3 + 0];
      nv_sh[tid * 3 + 1] = nvec[((size_t)g * 128 + tid) * 3 + 1];
      nv_sh[tid * 3 + 2] = nvec[((size_t)g * 128 + tid) * 3 + 2];
      w_sh[tid] = sqrtf(w[(size_t)g * 128 + tid]);
    }
    __syncthreads();
    const int n_l = tid >> 4, m0 = (tid & 15) * 8;
    float f0 = f_sh[n_l * 4 + 0], f1 = f_sh[n_l * 4 + 1], f2 = f_sh[n_l * 4 + 2];
    short8 pc, ps;
#pragma unroll
    for (int i = 0; i < 8; ++i) {
      int m = m0 + i;
      float dot = f0 * (float)nv_sh[m * 3] + f1 * (float)nv_sh[m * 3 + 1] +
                  f2 * (float)nv_sh[m * 3 + 2];
      float tr = dot - floorf(dot);
      float sn = __builtin_amdgcn_sinf(tr);
      float cs = __builtin_amdgcn_cosf(tr);
      float sq = w_sh[m];
      pc[i] = f2bf(sq * cs);
      ps[i] = f2bf(sq * sn);
    }
    const int node = g * NG_ + n0 + n_l;
    *(short8*)&CT[(size_t)node * 128 + m0] = pc;
    *(short8*)&ST[(size_t)node * 128 + m0] = ps;
  }
}

// ================= K_EV2: single-shot partial E*V over one 64-col chunk.
// 256 blocks: g = bid>>5, rowtile rt = (bid>>2)&7 (32 rows), colchunk cc = bid&3.
// Writes f32 partial [g][rt][cc][32][128].
__global__ __launch_bounds__(512) void k_EV2(
    const short* __restrict__ QA, const short* __restrict__ KA,
    const short* __restrict__ VT, const short* __restrict__ CT,
    const short* __restrict__ ST, float* __restrict__ PART) {
  __shared__ short smem[47104];  // 92 KB
  short* tQ  = smem;             // 32x128
  short* tCr = smem + 4096;
  short* tSr = smem + 8192;
  short* tKA = smem + 12288;     // 64x128
  short* tCc = smem + 20480;
  short* tSc = smem + 28672;
  short* tV  = smem + 36864;     // 128(d) x 64(n')
  short* tE  = smem + 45056;     // 32x64
  const int tid = threadIdx.x;
  const int bid = blockIdx.x;
  const int g = bid >> 5;
  const int rt = (bid >> 2) & 7;
  const int cc = bid & 3;
  const int R0 = rt * 32, C0 = cc * 64;
  const int gn = g * NG_;
  const int wid = tid >> 6, lane = tid & 63;
  const int frow = lane & 15, kq = (lane >> 4) * 8;
  const int orow = (lane >> 4) * 4, ocol = lane & 15;
  const int rfrag = wid >> 2;          // 0..1
  const int cfrag = wid & 3;           // 0..3 (E col frag / PV d block)

  // row-side staging: 512 threads cover 32x16 short8
  {
    int row = tid >> 4, c8 = (tid & 15) * 8;
    int idx = (row * 128 + c8) ^ ((row & 7) << 3);
    size_t ga = (size_t)(gn + R0 + row) * 128 + c8;
    *(short8*)&tQ[idx] = *(const short8*)&QA[ga];
    *(short8*)&tCr[idx] = *(const short8*)&CT[ga];
    *(short8*)&tSr[idx] = *(const short8*)&ST[ga];
  }
  // col-side staging: KA/Cc/Sc (64x128) + V (128x64)
#pragma unroll
  for (int it = 0; it < 2; ++it) {
    int e = tid + it * 512;
    int row = e >> 4, c8 = (e & 15) * 8;
    int idx = (row * 128 + c8) ^ ((row & 7) << 3);
    size_t ga = (size_t)(gn + C0 + row) * 128 + c8;
    *(short8*)&tKA[idx] = *(const short8*)&KA[ga];
    *(short8*)&tCc[idx] = *(const short8*)&CT[ga];
    *(short8*)&tSc[idx] = *(const short8*)&ST[ga];
    int d = e >> 3, n8 = (e & 7) * 8;
    *(short8*)&tV[(d * 64 + n8) ^ ((d & 7) << 3)] =
        *(const short8*)&VT[((size_t)g * 128 + d) * 256 + C0 + n8];
  }
  __syncthreads();
  // ---- E fragment: each wave one 16x16 frag at (rfrag, cfrag)
  f32x4 gc = {}, gs = {}, qc = {}, qs = {};
#pragma unroll
  for (int ks = 0; ks < 4; ++ks) {
    int kk = ks * 32 + kq, kk2 = (kk + 64) & 127;
    short8 aq = ldf(tQ, rfrag * 16 + frow, kk);
    short8 ka = ldf(tKA, cfrag * 16 + frow, kk);
    short8 t = ldf(tKA, cfrag * 16 + frow, kk2);
    short8 kb = (ks >= 2) ? neg8(t) : t;
    gc = MFMA16(aq, ka, gc);
    gs = MFMA16(aq, kb, gs);
  }
#pragma unroll
  for (int ks = 0; ks < 8; ++ks) {
    const bool lo = ks < 4;
    int kk = (ks & 3) * 32 + kq;
    short8 cr = ldf(tCr, rfrag * 16 + frow, kk);
    short8 sr = ldf(tSr, rfrag * 16 + frow, kk);
    short8 xr = lo ? cr : sr;
    short8 yr = lo ? sr : neg8(cr);
    short8 xc = ldf(lo ? tCc : tSc, cfrag * 16 + frow, kk);
    qc = MFMA16(xr, xc, qc);
    qs = MFMA16(yr, xc, qs);
  }
  // combine -> bounce E frag through LDS (bf16)
  {
    int col = cfrag * 16 + ocol;
#pragma unroll
    for (int r = 0; r < 4; ++r) {
      int row = rfrag * 16 + orow + r;
      float ev = gc[r] * qc[r] + gs[r] * qs[r];
      tE[(row * 64 + col) ^ ((row & 7) << 3)] = f2bf(ev);
    }
  }
  __syncthreads();
  // ---- PV partial: wave (rfrag, cfrag) -> rows rfrag*16, d cols cfrag*32..+31
  f32x4 oacc[2] = {};
#pragma unroll
  for (int ks = 0; ks < 2; ++ks) {
    int kk = ks * 32 + kq;
    short8 a = ldf64(tE, rfrag * 16 + frow, kk);
#pragma unroll
    for (int j = 0; j < 2; ++j) {
      short8 b = ldf64(tV, cfrag * 32 + j * 16 + frow, kk);
      oacc[j] = MFMA16(a, b, oacc[j]);
    }
  }
  float* pbase = PART + (size_t)bid * 32 * 128;
#pragma unroll
  for (int r = 0; r < 4; ++r) {
    int row = rfrag * 16 + orow + r;
#pragma unroll
    for (int j = 0; j < 2; ++j)
      pbase[row * 128 + cfrag * 32 + j * 16 + ocol] = oacc[j][r];
  }
}

// ================= K_red: out = GF*SCALE * sum_cc PART
__global__ __launch_bounds__(256) void k_red(
    const float* __restrict__ PART, const float* __restrict__ GF,
    float* __restrict__ out) {
  const int idx = blockIdx.x * 256 + threadIdx.x;  // < 65536
  const int node = idx >> 5;
  const int d4 = (idx & 31) * 4;
  const int grt = node >> 5;  // g*8 + rt
  const int nl = node & 31;
  const size_t base = (((size_t)grt * 4) * 32 + nl) * 128 + d4;
  float4 s = *(const float4*)&PART[base];
#pragma unroll
  for (int c = 1; c < 4; ++c) {
    float4 p = *(const float4*)&PART[base + (size_t)c * 32 * 128];
    s.x += p.x; s.y += p.y; s.z += p.z; s.w += p.w;
  }
  const float fct = GF[node] * SCALE_E;
  float4 o = {s.x * fct, s.y * fct, s.z * fct, s.w * fct};
  *(float4*)&out[(size_t)node * H_ + d4] = o;
}

extern "C" void kernel_launch(void* const* d_in, const int* in_sizes, int n_in,
                              void* d_out, int out_size, void* d_ws,
                              size_t ws_size, hipStream_t stream) {
  const float* node_feat = (const float*)d_in[0];
  const float* positions = (const float*)d_in[1];
  const float* cell = (const float*)d_in[2];
  const float* w = (const float*)d_in[3];
  const float* Wqkv = (const float*)d_in[4];
  const float* Wvg = (const float*)d_in[5];
  const float* bvg = (const float*)d_in[6];
  const float* Whg = (const float*)d_in[7];
  const float* bhg = (const float*)d_in[8];
  const float* Wmg = (const float*)d_in[9];
  const float* bmg = (const float*)d_in[10];
  const int* nvec = (const int*)d_in[11];
  float* out = (float*)d_out;
  char* ws = (char*)d_ws;

  short* QA = (short*)(ws + OFF_QA);
  short* KA = (short*)(ws + OFF_KA);
  short* VT = (short*)(ws + OFF_VT);
  short* CT = (short*)(ws + OFF_CT);
  short* ST = (short*)(ws + OFF_ST);
  float* GF = (float*)(ws + OFF_GF);
  float* PART = (float*)(ws + OFF_PART);
  float* out_gate = out + (size_t)NTOT_ * H_;

  k_prep<<<96, 512, 0, stream>>>(node_feat, Wqkv, Wvg, bvg, Whg, bhg, Wmg, bmg,
                                 cell, positions, nvec, w, QA, KA, VT, CT, ST,
                                 GF, out_gate);
  k_EV2<<<256, 512, 0, stream>>>(QA, KA, VT, CT, ST, PART);
  k_red<<<256, 256, 0, stream>>>(PART, GF, out);
}

// Round 7
// 23.770 us; speedup vs baseline: 2.8076x; 1.1677x over previous
//
#include <hip/hip_runtime.h>
#include <math.h>

using short8 = __attribute__((ext_vector_type(8))) short;
using f32x4 = __attribute__((ext_vector_type(4))) float;

#define MFMA16(a, b, c) __builtin_amdgcn_mfma_f32_16x16x32_bf16((a), (b), (c), 0, 0, 0)

namespace {
constexpr int NG_ = 256;
constexpr int H_ = 128;
constexpr int NTOT_ = 2048;
constexpr float SCALE_E = 0.08838834764831845f / 256.0f;  // (1/sqrt(H))/Ng

// workspace offsets in BYTES
constexpr size_t OFF_QA = 0;               // bf16 [2048][128] = [aq|bq]
constexpr size_t OFF_KA = 524288;          // bf16 [2048][128] = [ak|bk]
constexpr size_t OFF_VT = 1048576;         // bf16 [8][128][256] (d-major)
constexpr size_t OFF_CT = 1572864;         // bf16 [2048][128] sqrt(w)*cos
constexpr size_t OFF_ST = 2097152;         // bf16 [2048][128] sqrt(w)*sin
constexpr size_t OFF_GF = 2621440;         // f32 [2048]
}  // namespace

__device__ __forceinline__ short f2bf(float x) {
  unsigned u = __float_as_uint(x);
  unsigned r = (u + 0x7FFFu + ((u >> 16) & 1u)) >> 16;
  return (short)r;
}
__device__ __forceinline__ float bf2f(short x) {
  return __uint_as_float(((unsigned)(unsigned short)x) << 16);
}
__device__ __forceinline__ float sigmoidf_(float x) { return 1.0f / (1.0f + expf(-x)); }
__device__ __forceinline__ float siluf_(float x) { return x / (1.0f + expf(-x)); }

__device__ __forceinline__ short8 neg8(short8 x) {
  short8 r;
#pragma unroll
  for (int i = 0; i < 8; ++i) r[i] = (short)(x[i] ^ (short)0x8000);
  return r;
}
// fragment read from a [rows][128] bf16 LDS tile, XOR-swizzled
__device__ __forceinline__ short8 ldf(const short* buf, int row, int kk) {
  return *(const short8*)&buf[(row * 128 + kk) ^ ((row & 7) << 3)];
}
// fragment read from a [rows][64] bf16 LDS tile, XOR-swizzled
__device__ __forceinline__ short8 ldf64(const short* buf, int row, int kk) {
  return *(const short8*)&buf[(row * 64 + kk) ^ ((row & 7) << 3)];
}

// ================= K_prep: GEMM+activations (bid<64, 64x256 tiles)
//                  + trig tables & out-zeroing (bid 64..127)
__global__ __launch_bounds__(512) void k_prep(
    const float* __restrict__ nf, const float* __restrict__ Wqkv,
    const float* __restrict__ Wvg, const float* __restrict__ bvg,
    const float* __restrict__ Whg, const float* __restrict__ bhg,
    const float* __restrict__ Wmg, const float* __restrict__ bmg,
    const float* __restrict__ cell, const float* __restrict__ pos,
    const int* __restrict__ nvec, const float* __restrict__ w,
    short* __restrict__ QA, short* __restrict__ KA, short* __restrict__ VT,
    short* __restrict__ CT, short* __restrict__ ST, float* __restrict__ GF,
    float* __restrict__ out_gate, float* __restrict__ out_zero) {
  __shared__ short smem[40960];  // 80 KB
  const int tid = threadIdx.x;
  const int bid = blockIdx.x;
  if (bid < 64) {
    short* lA = smem;          // 64x128
    short* lB = smem + 8192;   // 256x128
    const int r_tile = bid >> 1, h = bid & 1;
    const int n0 = r_tile * 64, c0 = h * 256;
#pragma unroll
    for (int it = 0; it < 2; ++it) {
      int e = tid + it * 512;  // < 1024
      int row = e >> 4, c8 = (e & 15) * 8;
      const float* src = nf + (size_t)(n0 + row) * H_ + c8;
      float4 lo = *(const float4*)src, hi = *(const float4*)(src + 4);
      short8 v;
      v[0] = f2bf(lo.x); v[1] = f2bf(lo.y); v[2] = f2bf(lo.z); v[3] = f2bf(lo.w);
      v[4] = f2bf(hi.x); v[5] = f2bf(hi.y); v[6] = f2bf(hi.z); v[7] = f2bf(hi.w);
      *(short8*)&lA[(row * 128 + c8) ^ ((row & 7) << 3)] = v;
    }
#pragma unroll
    for (int it = 0; it < 8; ++it) {
      int e = tid + it * 512;  // < 4096
      int row = e >> 4, c8 = (e & 15) * 8;
      int wr_g = c0 + row;
      const float* src =
          (wr_g < 384 ? Wqkv + (size_t)wr_g * H_ : Wvg + (size_t)(wr_g - 384) * H_) + c8;
      float4 lo = *(const float4*)src, hi = *(const float4*)(src + 4);
      short8 v;
      v[0] = f2bf(lo.x); v[1] = f2bf(lo.y); v[2] = f2bf(lo.z); v[3] = f2bf(lo.w);
      v[4] = f2bf(hi.x); v[5] = f2bf(hi.y); v[6] = f2bf(hi.z); v[7] = f2bf(hi.w);
      *(short8*)&lB[(row * 128 + c8) ^ ((row & 7) << 3)] = v;
    }
    __syncthreads();
    const int wid = tid >> 6, lane = tid & 63;
    const int wrow = (wid >> 2) * 32, wcol = (wid & 3) * 64;
    const int frow = lane & 15, kq = (lane >> 4) * 8;
    f32x4 acc[2][4] = {};
#pragma unroll
    for (int ks = 0; ks < 4; ++ks) {
      int kk = ks * 32 + kq;
      short8 a[2], b[4];
#pragma unroll
      for (int i = 0; i < 2; ++i) a[i] = ldf(lA, wrow + i * 16 + frow, kk);
#pragma unroll
      for (int j = 0; j < 4; ++j) b[j] = ldf(lB, wcol + j * 16 + frow, kk);
#pragma unroll
      for (int i = 0; i < 2; ++i)
#pragma unroll
        for (int j = 0; j < 4; ++j) acc[i][j] = MFMA16(a[i], b[j], acc[i][j]);
    }
    const int orow = (lane >> 4) * 4, ocol = lane & 15;
    __syncthreads();
    if (h == 0) {
#pragma unroll
      for (int i = 0; i < 2; ++i)
#pragma unroll
        for (int j = 0; j < 4; ++j) {
          int c = wcol + j * 16 + ocol;
#pragma unroll
          for (int r = 0; r < 4; ++r) {
            int node = n0 + wrow + i * 16 + orow + r;
            float val = siluf_(acc[i][j][r]);
            if (c < 128)
              QA[(size_t)node * 128 + (c & 1) * 64 + (c >> 1)] = f2bf(val);
            else {
              int ck = c - 128;
              KA[(size_t)node * 128 + (ck & 1) * 64 + (ck >> 1)] = f2bf(val);
            }
          }
        }
    } else {
      short* gate_sh = lB;          // 64x128 bf16
      short* vt_sh = lB + 8192;     // 128(d) x 64(n), swizzled
      if (wcol >= 128) {
#pragma unroll
        for (int i = 0; i < 2; ++i)
#pragma unroll
          for (int j = 0; j < 4; ++j) {
            int d = wcol - 128 + j * 16 + ocol;
#pragma unroll
            for (int r = 0; r < 4; ++r) {
              int nl = wrow + i * 16 + orow + r;
              gate_sh[nl * 128 + d] = f2bf(sigmoidf_(acc[i][j][r] + bvg[d]));
            }
          }
      }
      __syncthreads();
      if (wcol < 128) {
#pragma unroll
        for (int i = 0; i < 2; ++i)
#pragma unroll
          for (int j = 0; j < 4; ++j) {
            int d = wcol + j * 16 + ocol;
#pragma unroll
            for (int r = 0; r < 4; ++r) {
              int nl = wrow + i * 16 + orow + r;
              float gate = bf2f(gate_sh[nl * 128 + d]);
              vt_sh[(d * 64 + nl) ^ ((d & 7) << 3)] = f2bf(acc[i][j][r] * gate);
            }
          }
      }
      __syncthreads();
      // coalesced VT write: [g][d][n] short8
      const int g_idx = n0 >> 8, nbase = n0 & 255;
#pragma unroll
      for (int it = 0; it < 2; ++it) {
        int e = tid + it * 512;  // < 1024
        int d = e >> 3, n8 = (e & 7) * 8;
        short8 v = *(const short8*)&vt_sh[(d * 64 + n8) ^ ((d & 7) << 3)];
        *(short8*)&VT[((size_t)(g_idx * 128 + d)) * 256 + nbase + n8] = v;
      }
      if (tid < 64) {
        int nl = tid;
        float hg = 0.f, mg = 0.f;
#pragma unroll 8
        for (int c = 0; c < 128; ++c) {
          float s = bf2f(lA[((nl * 128 + (c & ~7)) ^ ((nl & 7) << 3)) + (c & 7)]);
          hg += s * Whg[c];
          mg += s * Wmg[c];
        }
        int node = n0 + nl;
        GF[node] = 1.0f + 0.2f * tanhf(hg + bhg[0]);
        out_gate[node] = sigmoidf_(mg + bmg[0]);
      }
    }
  } else {
    const int b = bid - 64;
    const int g = b >> 3, n0 = (b & 7) * 32;
    // zero the update-output chunk (4096 floats per block)
    {
      float4 z = {0.f, 0.f, 0.f, 0.f};
      float* oz = out_zero + (size_t)b * 4096 + tid * 8;
      *(float4*)oz = z;
      *(float4*)(oz + 4) = z;
    }
    float* f_sh = (float*)smem;
    int* nv_sh = (int*)((char*)smem + 512);
    float* w_sh = (float*)((char*)smem + 2048);
    if (tid < 32) {
      const float* cg = cell + (size_t)g * 9;
      float A00 = cg[0], A01 = cg[3], A02 = cg[6];
      float A10 = cg[1], A11 = cg[4], A12 = cg[7];
      float A20 = cg[2], A21 = cg[5], A22 = cg[8];
      float b00 = A11 * A22 - A12 * A21;
      float b01 = A02 * A21 - A01 * A22;
      float b02 = A01 * A12 - A02 * A11;
      float b10 = A12 * A20 - A10 * A22;
      float b11 = A00 * A22 - A02 * A20;
      float b12 = A02 * A10 - A00 * A12;
      float b20 = A10 * A21 - A11 * A20;
      float b21 = A01 * A20 - A00 * A21;
      float b22 = A00 * A11 - A01 * A10;
      float det = A00 * b00 + A01 * b10 + A02 * b20;
      float inv = 1.0f / det;
      const int node = g * NG_ + n0 + tid;
      float p0 = pos[(size_t)node * 3 + 0];
      float p1 = pos[(size_t)node * 3 + 1];
      float p2 = pos[(size_t)node * 3 + 2];
      float f0 = (b00 * p0 + b01 * p1 + b02 * p2) * inv;
      float f1 = (b10 * p0 + b11 * p1 + b12 * p2) * inv;
      float f2 = (b20 * p0 + b21 * p1 + b22 * p2) * inv;
      f_sh[tid * 4 + 0] = f0 - floorf(f0);
      f_sh[tid * 4 + 1] = f1 - floorf(f1);
      f_sh[tid * 4 + 2] = f2 - floorf(f2);
    }
    if (tid < 128) {
      nv_sh[tid * 3 + 0] = nvec[((size_t)g * 128 + tid) * 3 + 0];
      nv_sh[tid * 3 + 1] = nvec[((size_t)g * 128 + tid) * 3 + 1];
      nv_sh[tid * 3 + 2] = nvec[((size_t)g * 128 + tid) * 3 + 2];
      w_sh[tid] = sqrtf(w[(size_t)g * 128 + tid]);
    }
    __syncthreads();
    const int n_l = tid >> 4, m0 = (tid & 15) * 8;
    float f0 = f_sh[n_l * 4 + 0], f1 = f_sh[n_l * 4 + 1], f2 = f_sh[n_l * 4 + 2];
    short8 pc, ps;
#pragma unroll
    for (int i = 0; i < 8; ++i) {
      int m = m0 + i;
      float dot = f0 * (float)nv_sh[m * 3] + f1 * (float)nv_sh[m * 3 + 1] +
                  f2 * (float)nv_sh[m * 3 + 2];
      float tr = dot - floorf(dot);
      float sn = __builtin_amdgcn_sinf(tr);
      float cs = __builtin_amdgcn_cosf(tr);
      float sq = w_sh[m];
      pc[i] = f2bf(sq * cs);
      ps[i] = f2bf(sq * sn);
    }
    const int node = g * NG_ + n0 + n_l;
    *(short8*)&CT[(size_t)node * 128 + m0] = pc;
    *(short8*)&ST[(size_t)node * 128 + m0] = ps;
  }
}

// ================= K_EV2: single-shot partial E*V over one 64-col chunk,
// gated + atomically accumulated into out (zeroed by k_prep).
__global__ __launch_bounds__(512) void k_EV2(
    const short* __restrict__ QA, const short* __restrict__ KA,
    const short* __restrict__ VT, const short* __restrict__ CT,
    const short* __restrict__ ST, const float* __restrict__ GF,
    float* __restrict__ out) {
  __shared__ short smem[47104];  // 92 KB
  short* tQ  = smem;             // 32x128
  short* tCr = smem + 4096;
  short* tSr = smem + 8192;
  short* tKA = smem + 12288;     // 64x128
  short* tCc = smem + 20480;
  short* tSc = smem + 28672;
  short* tV  = smem + 36864;     // 128(d) x 64(n')
  short* tE  = smem + 45056;     // 32x64
  const int tid = threadIdx.x;
  const int bid = blockIdx.x;
  const int g = bid >> 5;
  const int rt = (bid >> 2) & 7;
  const int cc = bid & 3;
  const int R0 = rt * 32, C0 = cc * 64;
  const int gn = g * NG_;
  const int wid = tid >> 6, lane = tid & 63;
  const int frow = lane & 15, kq = (lane >> 4) * 8;
  const int orow = (lane >> 4) * 4, ocol = lane & 15;
  const int rfrag = wid >> 2;          // 0..1
  const int cfrag = wid & 3;           // 0..3 (E col frag / PV d block)

  // row-side staging: 512 threads cover 32x16 short8
  {
    int row = tid >> 4, c8 = (tid & 15) * 8;
    int idx = (row * 128 + c8) ^ ((row & 7) << 3);
    size_t ga = (size_t)(gn + R0 + row) * 128 + c8;
    *(short8*)&tQ[idx] = *(const short8*)&QA[ga];
    *(short8*)&tCr[idx] = *(const short8*)&CT[ga];
    *(short8*)&tSr[idx] = *(const short8*)&ST[ga];
  }
  // col-side staging: KA/Cc/Sc (64x128) + V (128x64)
#pragma unroll
  for (int it = 0; it < 2; ++it) {
    int e = tid + it * 512;
    int row = e >> 4, c8 = (e & 15) * 8;
    int idx = (row * 128 + c8) ^ ((row & 7) << 3);
    size_t ga = (size_t)(gn + C0 + row) * 128 + c8;
    *(short8*)&tKA[idx] = *(const short8*)&KA[ga];
    *(short8*)&tCc[idx] = *(const short8*)&CT[ga];
    *(short8*)&tSc[idx] = *(const short8*)&ST[ga];
    int d = e >> 3, n8 = (e & 7) * 8;
    *(short8*)&tV[(d * 64 + n8) ^ ((d & 7) << 3)] =
        *(const short8*)&VT[((size_t)g * 128 + d) * 256 + C0 + n8];
  }
  __syncthreads();
  // ---- E fragment: each wave one 16x16 frag at (rfrag, cfrag)
  f32x4 gc = {}, gs = {}, qc = {}, qs = {};
#pragma unroll
  for (int ks = 0; ks < 4; ++ks) {
    int kk = ks * 32 + kq, kk2 = (kk + 64) & 127;
    short8 aq = ldf(tQ, rfrag * 16 + frow, kk);
    short8 ka = ldf(tKA, cfrag * 16 + frow, kk);
    short8 t = ldf(tKA, cfrag * 16 + frow, kk2);
    short8 kb = (ks >= 2) ? neg8(t) : t;
    gc = MFMA16(aq, ka, gc);
    gs = MFMA16(aq, kb, gs);
  }
#pragma unroll
  for (int ks = 0; ks < 8; ++ks) {
    const bool lo = ks < 4;
    int kk = (ks & 3) * 32 + kq;
    short8 cr = ldf(tCr, rfrag * 16 + frow, kk);
    short8 sr = ldf(tSr, rfrag * 16 + frow, kk);
    short8 xr = lo ? cr : sr;
    short8 yr = lo ? sr : neg8(cr);
    short8 xc = ldf(lo ? tCc : tSc, cfrag * 16 + frow, kk);
    qc = MFMA16(xr, xc, qc);
    qs = MFMA16(yr, xc, qs);
  }
  // combine -> bounce E frag through LDS (bf16)
  {
    int col = cfrag * 16 + ocol;
#pragma unroll
    for (int r = 0; r < 4; ++r) {
      int row = rfrag * 16 + orow + r;
      float ev = gc[r] * qc[r] + gs[r] * qs[r];
      tE[(row * 64 + col) ^ ((row & 7) << 3)] = f2bf(ev);
    }
  }
  __syncthreads();
  // ---- PV partial: wave (rfrag, cfrag) -> rows rfrag*16, d cols cfrag*32..+31
  f32x4 oacc[2] = {};
#pragma unroll
  for (int ks = 0; ks < 2; ++ks) {
    int kk = ks * 32 + kq;
    short8 a = ldf64(tE, rfrag * 16 + frow, kk);
#pragma unroll
    for (int j = 0; j < 2; ++j) {
      short8 b = ldf64(tV, cfrag * 32 + j * 16 + frow, kk);
      oacc[j] = MFMA16(a, b, oacc[j]);
    }
  }
  // gated atomic accumulate (gate is row-constant, distributes over the sum)
#pragma unroll
  for (int r = 0; r < 4; ++r) {
    int node = gn + R0 + rfrag * 16 + orow + r;
    float fct = GF[node] * SCALE_E;
#pragma unroll
    for (int j = 0; j < 2; ++j)
      unsafeAtomicAdd(&out[(size_t)node * H_ + cfrag * 32 + j * 16 + ocol],
                      oacc[j][r] * fct);
  }
}

extern "C" void kernel_launch(void* const* d_in, const int* in_sizes, int n_in,
                              void* d_out, int out_size, void* d_ws,
                              size_t ws_size, hipStream_t stream) {
  const float* node_feat = (const float*)d_in[0];
  const float* positions = (const float*)d_in[1];
  const float* cell = (const float*)d_in[2];
  const float* w = (const float*)d_in[3];
  const float* Wqkv = (const float*)d_in[4];
  const float* Wvg = (const float*)d_in[5];
  const float* bvg = (const float*)d_in[6];
  const float* Whg = (const float*)d_in[7];
  const float* bhg = (const float*)d_in[8];
  const float* Wmg = (const float*)d_in[9];
  const float* bmg = (const float*)d_in[10];
  const int* nvec = (const int*)d_in[11];
  float* out = (float*)d_out;
  char* ws = (char*)d_ws;

  short* QA = (short*)(ws + OFF_QA);
  short* KA = (short*)(ws + OFF_KA);
  short* VT = (short*)(ws + OFF_VT);
  short* CT = (short*)(ws + OFF_CT);
  short* ST = (short*)(ws + OFF_ST);
  float* GF = (float*)(ws + OFF_GF);
  float* out_gate = out + (size_t)NTOT_ * H_;

  k_prep<<<128, 512, 0, stream>>>(node_feat, Wqkv, Wvg, bvg, Whg, bhg, Wmg, bmg,
                                  cell, positions, nvec, w, QA, KA, VT, CT, ST,
                                  GF, out_gate, out);
  k_EV2<<<256, 512, 0, stream>>>(QA, KA, VT, CT, ST, GF, out);
}